// Round 5
// baseline (2355.176 us; speedup 1.0000x reference)
//
#include <hip/hip_runtime.h>
#include <hip/hip_bf16.h>

// LSTMReg on MI355X — round 5: fused 2-layer pipeline, SHORT MFMA CHAINS.
// 32 blocks x 512 thr (8 waves): waves 0-3 layer0 step t, waves 4-7 layer1
// step t-1. vs round 4: (a) L0's input-side projection (W_ih0·x[t+1]) is
// computed ONE ITERATION EARLY into a separate accumulator -> off the
// recurrence critical path; (b) each remaining side is split per k-tile into
// independent 3-deep MFMA chains (merged by f32x4 adds) instead of one
// 12-deep chain. MFMA count unchanged (48/wave/iter); dependent depth 12->3.
// bf16 hi/lo 3-pass numerics (absmax 2e-7, rounds 2-4).

typedef short bf16x8 __attribute__((ext_vector_type(8)));
typedef short bf16x4 __attribute__((ext_vector_type(4)));
typedef float f32x4  __attribute__((ext_vector_type(4)));

#define MFMA16(A, B, C) __builtin_amdgcn_mfma_f32_16x16x32_bf16(A, B, C, 0, 0, 0)

constexpr int T_LEN = 1024;
constexpr int H     = 64;
constexpr int NB    = 16;          // chains per block = MFMA N
constexpr int NTHR  = 512;         // 8 waves
constexpr int NBLK  = 32;          // 512 chains / 16

// x fragment buffer: [blk][t][lane(64)][frag(4)][8 shorts]; frag order
// k0h,k1h,k0l,k1l. 64 B per lane per t.
constexpr int    XT_SHORTS   = 64 * 32;                    // 2048
constexpr size_t XBLK_SHORTS = (size_t)T_LEN * XT_SHORTS;  // 4 MiB per block

__device__ __forceinline__ short f2bf(float f) {
  unsigned u = __builtin_bit_cast(unsigned, f);
  unsigned r = (u + 0x7fffu + ((u >> 16) & 1u)) >> 16;  // RNE
  return (short)r;
}
__device__ __forceinline__ float bf2f(short s) {
  unsigned u = ((unsigned)(unsigned short)s) << 16;
  return __builtin_bit_cast(float, u);
}
__device__ __forceinline__ float sigm(float x) { return 1.0f / (1.0f + __expf(-x)); }
__device__ __forceinline__ float tanhf_(float x) { return 1.0f - 2.0f / (1.0f + __expf(2.0f * x)); }

// ---- pre-pass: x [512][1024][64] fp32 -> fragment-order bf16 hi/lo ----
__global__ __launch_bounds__(256, 4) void xconv(const float* __restrict__ x,
                                                short* __restrict__ xf) {
  const int g  = blockIdx.x * 256 + threadIdx.x;  // (blk,b,t,lq), lq fastest
  const int lq = g & 3;
  const int t  = (g >> 2) & (T_LEN - 1);
  const int b  = (g >> 12) & 15;
  const int blk = g >> 16;
  const float* src = x + ((size_t)(blk * NB + b) * T_LEN + t) * H + 8 * lq;
  float4 v0 = *reinterpret_cast<const float4*>(src);
  float4 v1 = *reinterpret_cast<const float4*>(src + 4);
  float4 v2 = *reinterpret_cast<const float4*>(src + 32);
  float4 v3 = *reinterpret_cast<const float4*>(src + 36);
  float a[8] = {v0.x, v0.y, v0.z, v0.w, v1.x, v1.y, v1.z, v1.w};
  float c[8] = {v2.x, v2.y, v2.z, v2.w, v3.x, v3.y, v3.z, v3.w};
  bf16x8 k0h, k0l, k1h, k1l;
#pragma unroll
  for (int e = 0; e < 8; ++e) {
    short h0 = f2bf(a[e]);
    k0h[e] = h0;
    k0l[e] = f2bf(a[e] - bf2f(h0));
    short h1 = f2bf(c[e]);
    k1h[e] = h1;
    k1l[e] = f2bf(c[e] - bf2f(h1));
  }
  short* dst = xf + (size_t)blk * XBLK_SHORTS + (size_t)t * XT_SHORTS +
               (lq * 16 + b) * 32;
  *reinterpret_cast<bf16x8*>(dst + 0)  = k0h;
  *reinterpret_cast<bf16x8*>(dst + 8)  = k1h;
  *reinterpret_cast<bf16x8*>(dst + 16) = k0l;
  *reinterpret_cast<bf16x8*>(dst + 24) = k1l;
}

// 3-pass over ONE k-tile: 3 dependent MFMAs (hi·hi, lo·hi, hi·lo)
__device__ __forceinline__ f32x4 mfma3(bf16x8 wh, bf16x8 wl, bf16x8 kh,
                                       bf16x8 kl, f32x4 acc) {
  acc = MFMA16(wh, kh, acc);
  acc = MFMA16(wl, kh, acc);
  acc = MFMA16(wh, kl, acc);
  return acc;
}

__device__ __forceinline__ f32x4 lstm_gate(const f32x4 (&a)[4], f32x4& c) {
  f32x4 h;
#pragma unroll
  for (int r = 0; r < 4; ++r) {
    float ig = sigm(a[0][r]);
    float fg = sigm(a[1][r]);
    float gg = tanhf_(a[2][r]);
    float og = sigm(a[3][r]);
    float cc = fg * c[r] + ig * gg;
    c[r] = cc;
    h[r] = og * tanhf_(cc);
  }
  return h;
}

__global__ __launch_bounds__(NTHR, 2) void lstm_fused(
    const short* __restrict__ xf,
    const float* __restrict__ w_ih0, const float* __restrict__ w_hh0,
    const float* __restrict__ b_ih0, const float* __restrict__ b_hh0,
    const float* __restrict__ w_ih1, const float* __restrict__ w_hh1,
    const float* __restrict__ b_ih1, const float* __restrict__ b_hh1,
    const float* __restrict__ fc_w, const float* __restrict__ fc_b,
    float* __restrict__ out) {
  const int tid   = threadIdx.x;
  const int wv    = tid >> 6;
  const int group = wv >> 2;   // 0 = layer0, 1 = layer1
  const int sw    = wv & 3;    // h-row slice 16*sw..16*sw+15
  const int l     = tid & 63;
  const int b     = l & 15;    // chain (MFMA col)
  const int lq    = l >> 4;    // k-quarter / D-row-quarter
  const int blk   = blockIdx.x;
  const int chain0 = blk * NB;

  // fragment-linear h buffers: [buf][part(hi/lo)][kts][lane][8 shorts]
  __shared__ __align__(16) short h0buf[2][2][2][64][8];  // 8 KiB
  __shared__ __align__(16) short h1buf[2][2][2][64][8];  // 8 KiB
  __shared__ __align__(16) float bias_s[2][256];
  __shared__ float fcw_s[H];
  __shared__ float hfin[NB][H];

  for (int i = tid; i < 2 * 2 * 2 * 64 * 8; i += NTHR) {
    ((short*)h0buf)[i] = 0;
    ((short*)h1buf)[i] = 0;
  }
  if (tid < 256)      bias_s[0][tid] = b_ih0[tid] + b_hh0[tid];
  else                bias_s[1][tid - 256] = b_ih1[tid - 256] + b_hh1[tid - 256];
  if (tid < H) fcw_s[tid] = fc_w[tid];

  // ---- this wave's layer weights -> register frags (hi/lo) ----
  const float* wih = group ? w_ih1 : w_ih0;
  const float* whh = group ? w_hh1 : w_hh0;
  bf16x8 whi[4][4], wlo[4][4];  // [gate][kt] = 128 regs
#pragma unroll
  for (int g = 0; g < 4; ++g) {
#pragma unroll
    for (int kt = 0; kt < 4; ++kt) {
      const int row = 64 * g + 16 * sw + b;
      const int k0  = 32 * kt + 8 * lq;
      const float* src = (k0 < 64) ? &wih[row * 64 + k0] : &whh[row * 64 + (k0 - 64)];
      float4 v0 = *reinterpret_cast<const float4*>(src);
      float4 v1 = *reinterpret_cast<const float4*>(src + 4);
      float vv[8] = {v0.x, v0.y, v0.z, v0.w, v1.x, v1.y, v1.z, v1.w};
      bf16x8 hi8, lo8;
#pragma unroll
      for (int e = 0; e < 8; ++e) {
        short hh = f2bf(vv[e]);
        hi8[e] = hh;
        lo8[e] = f2bf(vv[e] - bf2f(hh));
      }
      whi[g][kt] = hi8;
      wlo[g][kt] = lo8;
    }
  }

  __syncthreads();  // bias_s / h-buf zeros visible

  // ---- G0 prologue: accx = bias + W_ih0·x[0]; xc = x[1] packet ----
  const short* xfl = xf + (size_t)blk * XBLK_SHORTS + (size_t)l * 32;
  f32x4 accx[4];
  bf16x8 xc0h, xc1h, xc0l, xc1l;  // x[t+1] (precompute source)
  bf16x8 xn0h, xn1h, xn0l, xn1l;  // x[t+2] (in flight)
  if (group == 0) {
    bf16x8 a0h = *reinterpret_cast<const bf16x8*>(xfl + 0);
    bf16x8 a1h = *reinterpret_cast<const bf16x8*>(xfl + 8);
    bf16x8 a0l = *reinterpret_cast<const bf16x8*>(xfl + 16);
    bf16x8 a1l = *reinterpret_cast<const bf16x8*>(xfl + 24);
#pragma unroll
    for (int g = 0; g < 4; ++g) {
      f32x4 acc = *reinterpret_cast<const f32x4*>(&bias_s[0][64 * g + 16 * sw + 4 * lq]);
      acc = mfma3(whi[g][0], wlo[g][0], a0h, a0l, acc);
      acc = mfma3(whi[g][1], wlo[g][1], a1h, a1l, acc);
      accx[g] = acc;
    }
    const short* p = xfl + XT_SHORTS;  // x[1]
    xc0h = *reinterpret_cast<const bf16x8*>(p + 0);
    xc1h = *reinterpret_cast<const bf16x8*>(p + 8);
    xc0l = *reinterpret_cast<const bf16x8*>(p + 16);
    xc1l = *reinterpret_cast<const bf16x8*>(p + 24);
  }

  f32x4 creg = {0.f, 0.f, 0.f, 0.f};
  // h write mapping (verified round 4): feature f = 16sw+4lq+r
  const int w_kts = sw >> 1;
  const int w_li  = (2 * (sw & 1) + (lq >> 1)) * 16 + b;
  const int w_e0  = 4 * (lq & 1);
  const int hoff  = 16 * sw + 4 * lq;
  const f32x4 zf4 = {0.f, 0.f, 0.f, 0.f};

  for (int t = 0; t <= T_LEN; ++t) {
    const int cur = t & 1, nxt = cur ^ 1;

    // h0[t-1] frags: L0 recurrent side, L1 input side (conflict-free b128)
    const short* p0 = &h0buf[cur][0][0][l][0];
    bf16x8 r0h = *reinterpret_cast<const bf16x8*>(p0);
    bf16x8 r1h = *reinterpret_cast<const bf16x8*>(p0 + 512);
    bf16x8 r0l = *reinterpret_cast<const bf16x8*>(p0 + 1024);
    bf16x8 r1l = *reinterpret_cast<const bf16x8*>(p0 + 1536);

    if (group == 0) {
      // issue x[t+2] load early (covered by this iter's compute)
      if (t + 2 < T_LEN) {
        const short* p = xfl + (size_t)(t + 2) * XT_SHORTS;
        xn0h = *reinterpret_cast<const bf16x8*>(p + 0);
        xn1h = *reinterpret_cast<const bf16x8*>(p + 8);
        xn0l = *reinterpret_cast<const bf16x8*>(p + 16);
        xn1l = *reinterpret_cast<const bf16x8*>(p + 24);
      }
      if (t < T_LEN) {
        // recurrent side: two independent 3-deep chains per gate
        f32x4 aR0[4], aR1[4], a[4];
#pragma unroll
        for (int g = 0; g < 4; ++g) {
          aR0[g] = mfma3(whi[g][2], wlo[g][2], r0h, r0l, zf4);
          aR1[g] = mfma3(whi[g][3], wlo[g][3], r1h, r1l, zf4);
        }
#pragma unroll
        for (int g = 0; g < 4; ++g) a[g] = (accx[g] + aR0[g]) + aR1[g];
        f32x4 hnew = lstm_gate(a, creg);
        bf16x4 h4, l4;
#pragma unroll
        for (int r = 0; r < 4; ++r) {
          short hh = f2bf(hnew[r]);
          h4[r] = hh;
          l4[r] = f2bf(hnew[r] - bf2f(hh));
        }
        short* dst = &h0buf[nxt][0][0][0][0] + w_kts * 512 + w_li * 8 + w_e0;
        *reinterpret_cast<bf16x4*>(dst)        = h4;
        *reinterpret_cast<bf16x4*>(dst + 1024) = l4;
        // precompute next step's input side (independent of this iter's rec)
        if (t + 1 < T_LEN) {
#pragma unroll
          for (int g = 0; g < 4; ++g) {
            f32x4 acc = *reinterpret_cast<const f32x4*>(&bias_s[0][64 * g + 16 * sw + 4 * lq]);
            acc = mfma3(whi[g][0], wlo[g][0], xc0h, xc0l, acc);
            acc = mfma3(whi[g][1], wlo[g][1], xc1h, xc1l, acc);
            accx[g] = acc;
          }
        }
      }
    } else {
      // h1[t-2] frags: L1 recurrent side
      const short* p1 = &h1buf[cur][0][0][l][0];
      bf16x8 s0h = *reinterpret_cast<const bf16x8*>(p1);
      bf16x8 s1h = *reinterpret_cast<const bf16x8*>(p1 + 512);
      bf16x8 s0l = *reinterpret_cast<const bf16x8*>(p1 + 1024);
      bf16x8 s1l = *reinterpret_cast<const bf16x8*>(p1 + 1536);
      if (t >= 1) {
        // four independent 3-deep chains per gate
        f32x4 aI0[4], aI1[4], aR0[4], aR1[4], a[4];
#pragma unroll
        for (int g = 0; g < 4; ++g) {
          f32x4 bi = *reinterpret_cast<const f32x4*>(&bias_s[1][64 * g + 16 * sw + 4 * lq]);
          aI0[g] = mfma3(whi[g][0], wlo[g][0], r0h, r0l, bi);
          aI1[g] = mfma3(whi[g][1], wlo[g][1], r1h, r1l, zf4);
          aR0[g] = mfma3(whi[g][2], wlo[g][2], s0h, s0l, zf4);
          aR1[g] = mfma3(whi[g][3], wlo[g][3], s1h, s1l, zf4);
        }
#pragma unroll
        for (int g = 0; g < 4; ++g) a[g] = (aI0[g] + aI1[g]) + (aR0[g] + aR1[g]);
        f32x4 hnew = lstm_gate(a, creg);
        if (t == T_LEN) {
#pragma unroll
          for (int r = 0; r < 4; ++r) hfin[b][hoff + r] = hnew[r];
        } else {
          bf16x4 h4, l4;
#pragma unroll
          for (int r = 0; r < 4; ++r) {
            short hh = f2bf(hnew[r]);
            h4[r] = hh;
            l4[r] = f2bf(hnew[r] - bf2f(hh));
          }
          short* dst = &h1buf[nxt][0][0][0][0] + w_kts * 512 + w_li * 8 + w_e0;
          *reinterpret_cast<bf16x4*>(dst)        = h4;
          *reinterpret_cast<bf16x4*>(dst + 1024) = l4;
        }
      }
    }

    __syncthreads();

    if (group == 0) { xc0h = xn0h; xc1h = xn1h; xc0l = xn0l; xc1l = xn1l; }
  }

  // ---- FC epilogue: out = fc_w . h2[T-1] + fc_b ----
  if (tid < NB) {
    float acc = fc_b[0];
#pragma unroll
    for (int h = 0; h < H; ++h) acc += fcw_s[h] * hfin[tid][h];
    out[chain0 + tid] = acc;
  }
}

extern "C" void kernel_launch(void* const* d_in, const int* in_sizes, int n_in,
                              void* d_out, int out_size, void* d_ws, size_t ws_size,
                              hipStream_t stream) {
  const float* x     = (const float*)d_in[0];
  const float* w_ih0 = (const float*)d_in[1];
  const float* w_hh0 = (const float*)d_in[2];
  const float* b_ih0 = (const float*)d_in[3];
  const float* b_hh0 = (const float*)d_in[4];
  const float* w_ih1 = (const float*)d_in[5];
  const float* w_hh1 = (const float*)d_in[6];
  const float* b_ih1 = (const float*)d_in[7];
  const float* b_hh1 = (const float*)d_in[8];
  const float* fc_w  = (const float*)d_in[9];
  const float* fc_b  = (const float*)d_in[10];
  float* out = (float*)d_out;

  short* xfrag = (short*)d_ws;  // 128 MiB (availability proven round 1)

  xconv<<<dim3(8192), dim3(256), 0, stream>>>(x, xfrag);
  lstm_fused<<<dim3(NBLK), dim3(NTHR), 0, stream>>>(
      xfrag, w_ih0, w_hh0, b_ih0, b_hh0, w_ih1, w_hh1, b_ih1, b_hh1,
      fc_w, fc_b, out);
}

// Round 6
// 2292.098 us; speedup vs baseline: 1.0275x; 1.0275x over previous
//
#include <hip/hip_runtime.h>
#include <hip/hip_bf16.h>

// LSTMReg on MI355X — round 6: FILL ALL 256 CUs (DVFS fix).
// Rounds 2-5 ran 32 blocks -> ~12% CU utilization -> chip parked at ~650 MHz
// (MfmaUtil & VALUBusy both consistent with ~1450-cyc iterations at 28%/65%
// active-CU issue). Same per-CU issue load, spread as NB=2 chains x 256
// blocks (MFMA cost per group is independent of chains-per-group), 1 block/CU
// enforced via 64KB LDS pad. Structure otherwise = round 5 (layer-split
// waves, precomputed input-side, 3-deep chains, bf16 hi/lo 3-pass).

typedef short bf16x8 __attribute__((ext_vector_type(8)));
typedef short bf16x4 __attribute__((ext_vector_type(4)));
typedef float f32x4  __attribute__((ext_vector_type(4)));

#define MFMA16(A, B, C) __builtin_amdgcn_mfma_f32_16x16x32_bf16(A, B, C, 0, 0, 0)

constexpr int T_LEN = 1024;
constexpr int H     = 64;
constexpr int NB    = 2;            // chains per block (cols 2..15 of MFMA unused)
constexpr int NTHR  = 512;          // 8 waves
constexpr int NBLK  = 256;          // 512 chains / 2 -> one block per CU

// x fragment buffer: [blk][t][packet(lq*NB+c)][32 shorts]; packet = k0h,k1h,k0l,k1l
constexpr int    XT_SHORTS   = NB * 4 * 32;                // 256 shorts (512 B) per t
constexpr size_t XBLK_SHORTS = (size_t)T_LEN * XT_SHORTS;  // 512 KiB per block

__device__ __forceinline__ short f2bf(float f) {
  unsigned u = __builtin_bit_cast(unsigned, f);
  unsigned r = (u + 0x7fffu + ((u >> 16) & 1u)) >> 16;  // RNE
  return (short)r;
}
__device__ __forceinline__ float bf2f(short s) {
  unsigned u = ((unsigned)(unsigned short)s) << 16;
  return __builtin_bit_cast(float, u);
}
__device__ __forceinline__ float sigm(float x) { return 1.0f / (1.0f + __expf(-x)); }
__device__ __forceinline__ float tanhf_(float x) { return 1.0f - 2.0f / (1.0f + __expf(2.0f * x)); }

// ---- pre-pass: x [512][1024][64] fp32 -> per-block packet order bf16 hi/lo ----
__global__ __launch_bounds__(256, 4) void xconv(const float* __restrict__ x,
                                                short* __restrict__ xf) {
  const int g  = blockIdx.x * 256 + threadIdx.x;  // one thread per (chain,t,lq)
  const int lq = g & 3;
  const int t  = (g >> 2) & (T_LEN - 1);
  const int chain = g >> 12;                      // 0..511
  const int c   = chain & 1;
  const int blk = chain >> 1;
  const float* src = x + ((size_t)chain * T_LEN + t) * H + 8 * lq;
  float4 v0 = *reinterpret_cast<const float4*>(src);
  float4 v1 = *reinterpret_cast<const float4*>(src + 4);
  float4 v2 = *reinterpret_cast<const float4*>(src + 32);
  float4 v3 = *reinterpret_cast<const float4*>(src + 36);
  float a[8] = {v0.x, v0.y, v0.z, v0.w, v1.x, v1.y, v1.z, v1.w};
  float c8[8] = {v2.x, v2.y, v2.z, v2.w, v3.x, v3.y, v3.z, v3.w};
  bf16x8 k0h, k0l, k1h, k1l;
#pragma unroll
  for (int e = 0; e < 8; ++e) {
    short h0 = f2bf(a[e]);
    k0h[e] = h0;
    k0l[e] = f2bf(a[e] - bf2f(h0));
    short h1 = f2bf(c8[e]);
    k1h[e] = h1;
    k1l[e] = f2bf(c8[e] - bf2f(h1));
  }
  short* dst = xf + (size_t)blk * XBLK_SHORTS + (size_t)t * XT_SHORTS +
               (lq * NB + c) * 32;
  *reinterpret_cast<bf16x8*>(dst + 0)  = k0h;
  *reinterpret_cast<bf16x8*>(dst + 8)  = k1h;
  *reinterpret_cast<bf16x8*>(dst + 16) = k0l;
  *reinterpret_cast<bf16x8*>(dst + 24) = k1l;
}

// 3-pass over ONE k-tile: hi·hi, lo·hi, hi·lo
__device__ __forceinline__ f32x4 mfma3(bf16x8 wh, bf16x8 wl, bf16x8 kh,
                                       bf16x8 kl, f32x4 acc) {
  acc = MFMA16(wh, kh, acc);
  acc = MFMA16(wl, kh, acc);
  acc = MFMA16(wh, kl, acc);
  return acc;
}

__device__ __forceinline__ f32x4 lstm_gate(const f32x4 (&a)[4], f32x4& c) {
  f32x4 h;
#pragma unroll
  for (int r = 0; r < 4; ++r) {
    float ig = sigm(a[0][r]);
    float fg = sigm(a[1][r]);
    float gg = tanhf_(a[2][r]);
    float og = sigm(a[3][r]);
    float cc = fg * c[r] + ig * gg;
    c[r] = cc;
    h[r] = og * tanhf_(cc);
  }
  return h;
}

__global__ __launch_bounds__(NTHR, 2) void lstm_fused(
    const short* __restrict__ xf,
    const float* __restrict__ w_ih0, const float* __restrict__ w_hh0,
    const float* __restrict__ b_ih0, const float* __restrict__ b_hh0,
    const float* __restrict__ w_ih1, const float* __restrict__ w_hh1,
    const float* __restrict__ b_ih1, const float* __restrict__ b_hh1,
    const float* __restrict__ fc_w, const float* __restrict__ fc_b,
    float* __restrict__ out) {
  const int tid   = threadIdx.x;
  const int wv    = tid >> 6;
  const int group = wv >> 2;   // 0 = layer0, 1 = layer1
  const int sw    = wv & 3;    // h-row slice 16*sw..16*sw+15
  const int l     = tid & 63;
  const int b     = l & 15;    // MFMA col; real chains are b<NB
  const int lq    = l >> 4;    // k-quarter / D-row-quarter
  const int blk   = blockIdx.x;
  const int chain0 = blk * NB;

  // h buffers: [buf][part(hi/lo)][kts][phys 544 shorts]
  // slot li (0..63) at phys offset li*8 + (li>>4)*8 (16B pad per 16 slots)
  __shared__ __align__(16) short h0buf[2][2][2][544];  // 8704 B
  __shared__ __align__(16) short h1buf[2][2][2][544];  // 8704 B
  __shared__ __align__(16) float bias_s[2][256];
  __shared__ float fcw_s[H];
  __shared__ float hfin[NB][H];
  __shared__ volatile char lds_pad[64 * 1024];  // force 1 block/CU (>80KB total)

  for (int i = tid; i < 2 * 2 * 2 * 544; i += NTHR) {
    ((short*)h0buf)[i] = 0;
    ((short*)h1buf)[i] = 0;
  }
  if (tid < 64) lds_pad[tid] = 0;
  if (tid < 256)      bias_s[0][tid] = b_ih0[tid] + b_hh0[tid];
  else                bias_s[1][tid - 256] = b_ih1[tid - 256] + b_hh1[tid - 256];
  if (tid < H) fcw_s[tid] = fc_w[tid];

  // ---- this wave's layer weights -> register frags (hi/lo) ----
  const float* wih = group ? w_ih1 : w_ih0;
  const float* whh = group ? w_hh1 : w_hh0;
  bf16x8 whi[4][4], wlo[4][4];  // [gate][kt] = 128 regs
#pragma unroll
  for (int g = 0; g < 4; ++g) {
#pragma unroll
    for (int kt = 0; kt < 4; ++kt) {
      const int row = 64 * g + 16 * sw + b;
      const int k0  = 32 * kt + 8 * lq;
      const float* src = (k0 < 64) ? &wih[row * 64 + k0] : &whh[row * 64 + (k0 - 64)];
      float4 v0 = *reinterpret_cast<const float4*>(src);
      float4 v1 = *reinterpret_cast<const float4*>(src + 4);
      float vv[8] = {v0.x, v0.y, v0.z, v0.w, v1.x, v1.y, v1.z, v1.w};
      bf16x8 hi8, lo8;
#pragma unroll
      for (int e = 0; e < 8; ++e) {
        short hh = f2bf(vv[e]);
        hi8[e] = hh;
        lo8[e] = f2bf(vv[e] - bf2f(hh));
      }
      whi[g][kt] = hi8;
      wlo[g][kt] = lo8;
    }
  }

  __syncthreads();  // bias_s / h-buf zeros visible

  // ---- G0 prologue: accx = bias + W_ih0·x[0]; xc = x[1] packet ----
  // lane l reads packet for chain (l&1), quarter lq
  const short* xfl = xf + (size_t)blk * XBLK_SHORTS + (size_t)(lq * NB + (l & 1)) * 32;
  f32x4 accx[4];
  bf16x8 xc0h, xc1h, xc0l, xc1l;  // x[t+1] (precompute source)
  bf16x8 xn0h, xn1h, xn0l, xn1l;  // x[t+2] (in flight)
  if (group == 0) {
    bf16x8 a0h = *reinterpret_cast<const bf16x8*>(xfl + 0);
    bf16x8 a1h = *reinterpret_cast<const bf16x8*>(xfl + 8);
    bf16x8 a0l = *reinterpret_cast<const bf16x8*>(xfl + 16);
    bf16x8 a1l = *reinterpret_cast<const bf16x8*>(xfl + 24);
#pragma unroll
    for (int g = 0; g < 4; ++g) {
      f32x4 acc = *reinterpret_cast<const f32x4*>(&bias_s[0][64 * g + 16 * sw + 4 * lq]);
      acc = mfma3(whi[g][0], wlo[g][0], a0h, a0l, acc);
      acc = mfma3(whi[g][1], wlo[g][1], a1h, a1l, acc);
      accx[g] = acc;
    }
    const short* p = xfl + XT_SHORTS;  // x[1]
    xc0h = *reinterpret_cast<const bf16x8*>(p + 0);
    xc1h = *reinterpret_cast<const bf16x8*>(p + 8);
    xc0l = *reinterpret_cast<const bf16x8*>(p + 16);
    xc1l = *reinterpret_cast<const bf16x8*>(p + 24);
  }

  f32x4 creg = {0.f, 0.f, 0.f, 0.f};
  // reader phys offset: slot li_r = (l>>4)*16 + (l&1) -> li_r*8 + (l>>4)*8
  const int rslot = (l >> 4) * 136 + (l & 1) * 8;
  // writer (b<NB): feature f = 16sw+4lq+r; quarter wq = 2(sw&1)+(lq>>1)
  const int wq    = 2 * (sw & 1) + (lq >> 1);
  const int w_kts = sw >> 1;
  const int woff  = (wq * 16 + b) * 8 + wq * 8 + 4 * (lq & 1);
  const int hoff  = 16 * sw + 4 * lq;
  const f32x4 zf4 = {0.f, 0.f, 0.f, 0.f};

  for (int t = 0; t <= T_LEN; ++t) {
    const int cur = t & 1, nxt = cur ^ 1;

    // h0[t-1] frags: L0 recurrent side, L1 input side (2-way max bank alias)
    const short* p0 = &h0buf[cur][0][0][0] + rslot;
    bf16x8 r0h = *reinterpret_cast<const bf16x8*>(p0);          // part0 kts0
    bf16x8 r1h = *reinterpret_cast<const bf16x8*>(p0 + 544);    // part0 kts1
    bf16x8 r0l = *reinterpret_cast<const bf16x8*>(p0 + 1088);   // part1 kts0
    bf16x8 r1l = *reinterpret_cast<const bf16x8*>(p0 + 1632);   // part1 kts1

    if (group == 0) {
      if (t + 2 < T_LEN) {  // issue x[t+2] load early
        const short* p = xfl + (size_t)(t + 2) * XT_SHORTS;
        xn0h = *reinterpret_cast<const bf16x8*>(p + 0);
        xn1h = *reinterpret_cast<const bf16x8*>(p + 8);
        xn0l = *reinterpret_cast<const bf16x8*>(p + 16);
        xn1l = *reinterpret_cast<const bf16x8*>(p + 24);
      }
      if (t < T_LEN) {
        // recurrent side: two independent 3-deep chains per gate
        f32x4 aR0[4], aR1[4], a[4];
#pragma unroll
        for (int g = 0; g < 4; ++g) {
          aR0[g] = mfma3(whi[g][2], wlo[g][2], r0h, r0l, zf4);
          aR1[g] = mfma3(whi[g][3], wlo[g][3], r1h, r1l, zf4);
        }
#pragma unroll
        for (int g = 0; g < 4; ++g) a[g] = (accx[g] + aR0[g]) + aR1[g];
        f32x4 hnew = lstm_gate(a, creg);
        if (b < NB) {
          bf16x4 h4, l4;
#pragma unroll
          for (int r = 0; r < 4; ++r) {
            short hh = f2bf(hnew[r]);
            h4[r] = hh;
            l4[r] = f2bf(hnew[r] - bf2f(hh));
          }
          short* dst = &h0buf[nxt][0][w_kts][0] + woff;
          *reinterpret_cast<bf16x4*>(dst)        = h4;
          *reinterpret_cast<bf16x4*>(dst + 1088) = l4;
        }
        // precompute next step's input side
        if (t + 1 < T_LEN) {
#pragma unroll
          for (int g = 0; g < 4; ++g) {
            f32x4 acc = *reinterpret_cast<const f32x4*>(&bias_s[0][64 * g + 16 * sw + 4 * lq]);
            acc = mfma3(whi[g][0], wlo[g][0], xc0h, xc0l, acc);
            acc = mfma3(whi[g][1], wlo[g][1], xc1h, xc1l, acc);
            accx[g] = acc;
          }
        }
      }
    } else {
      // h1[t-2] frags: L1 recurrent side
      const short* p1 = &h1buf[cur][0][0][0] + rslot;
      bf16x8 s0h = *reinterpret_cast<const bf16x8*>(p1);
      bf16x8 s1h = *reinterpret_cast<const bf16x8*>(p1 + 544);
      bf16x8 s0l = *reinterpret_cast<const bf16x8*>(p1 + 1088);
      bf16x8 s1l = *reinterpret_cast<const bf16x8*>(p1 + 1632);
      if (t >= 1) {
        f32x4 aI0[4], aI1[4], aR0[4], aR1[4], a[4];
#pragma unroll
        for (int g = 0; g < 4; ++g) {
          f32x4 bi = *reinterpret_cast<const f32x4*>(&bias_s[1][64 * g + 16 * sw + 4 * lq]);
          aI0[g] = mfma3(whi[g][0], wlo[g][0], r0h, r0l, bi);
          aI1[g] = mfma3(whi[g][1], wlo[g][1], r1h, r1l, zf4);
          aR0[g] = mfma3(whi[g][2], wlo[g][2], s0h, s0l, zf4);
          aR1[g] = mfma3(whi[g][3], wlo[g][3], s1h, s1l, zf4);
        }
#pragma unroll
        for (int g = 0; g < 4; ++g) a[g] = (aI0[g] + aI1[g]) + (aR0[g] + aR1[g]);
        f32x4 hnew = lstm_gate(a, creg);
        if (t == T_LEN) {
          if (b < NB) {
#pragma unroll
            for (int r = 0; r < 4; ++r) hfin[b][hoff + r] = hnew[r];
          }
        } else if (b < NB) {
          bf16x4 h4, l4;
#pragma unroll
          for (int r = 0; r < 4; ++r) {
            short hh = f2bf(hnew[r]);
            h4[r] = hh;
            l4[r] = f2bf(hnew[r] - bf2f(hh));
          }
          short* dst = &h1buf[nxt][0][w_kts][0] + woff;
          *reinterpret_cast<bf16x4*>(dst)        = h4;
          *reinterpret_cast<bf16x4*>(dst + 1088) = l4;
        }
      }
    }

    __syncthreads();

    if (group == 0) { xc0h = xn0h; xc1h = xn1h; xc0l = xn0l; xc1l = xn1l; }
  }

  // ---- FC epilogue: out = fc_w . h2[T-1] + fc_b ----
  if (tid < NB) {
    float acc = fc_b[0];
#pragma unroll
    for (int h = 0; h < H; ++h) acc += fcw_s[h] * hfin[tid][h];
    out[chain0 + tid] = acc;
  }
}

extern "C" void kernel_launch(void* const* d_in, const int* in_sizes, int n_in,
                              void* d_out, int out_size, void* d_ws, size_t ws_size,
                              hipStream_t stream) {
  const float* x     = (const float*)d_in[0];
  const float* w_ih0 = (const float*)d_in[1];
  const float* w_hh0 = (const float*)d_in[2];
  const float* b_ih0 = (const float*)d_in[3];
  const float* b_hh0 = (const float*)d_in[4];
  const float* w_ih1 = (const float*)d_in[5];
  const float* w_hh1 = (const float*)d_in[6];
  const float* b_ih1 = (const float*)d_in[7];
  const float* b_hh1 = (const float*)d_in[8];
  const float* fc_w  = (const float*)d_in[9];
  const float* fc_b  = (const float*)d_in[10];
  float* out = (float*)d_out;

  short* xfrag = (short*)d_ws;  // 128 MiB (availability proven rounds 4-5)

  xconv<<<dim3(8192), dim3(256), 0, stream>>>(x, xfrag);
  lstm_fused<<<dim3(NBLK), dim3(NTHR), 0, stream>>>(
      xfrag, w_ih0, w_hh0, b_ih0, b_hh0, w_ih1, w_hh1, b_ih1, b_hh1,
      fc_w, fc_b, out);
}

// Round 7
// 2171.252 us; speedup vs baseline: 1.0847x; 1.0557x over previous
//
#include <hip/hip_runtime.h>
#include <hip/hip_bf16.h>

// LSTMReg on MI355X — round 7: gate-redistribution + cheap nonlinearities.
// Round 6 proved the chip saturates (MfmaUtil+VALUBusy ~95%) with VALU
// dominant (66%): IEEE-divide gate math, computed redundantly by all 64
// lanes. This round: (1) z goes through a 4KB LDS buffer; 256 gate threads
// (the L1 waves) each handle ONE (layer,chain,h) task -> gate VALU /8;
// (2) sigmoid/tanh via rcp(1+__expf(x)) (__builtin_amdgcn_rcpf) -> no IEEE
// div sequence; (3) L0's input-side precompute MFMAs overlap the gate phase
// (separate wave on the SIMD). Verified h-frag LDS mapping kept bit-for-bit.

typedef short bf16x8 __attribute__((ext_vector_type(8)));
typedef float f32x4  __attribute__((ext_vector_type(4)));

#define MFMA16(A, B, C) __builtin_amdgcn_mfma_f32_16x16x32_bf16(A, B, C, 0, 0, 0)

constexpr int T_LEN = 1024;
constexpr int H     = 64;
constexpr int NB    = 2;            // chains per block
constexpr int NTHR  = 512;          // 8 waves
constexpr int NBLK  = 256;          // one block per CU

// x fragment buffer: [blk][t][packet(lq*NB+c)][32 shorts]; packet = k0h,k1h,k0l,k1l
constexpr int    XT_SHORTS   = NB * 4 * 32;                // 256 shorts per t
constexpr size_t XBLK_SHORTS = (size_t)T_LEN * XT_SHORTS;  // 512 KiB per block

__device__ __forceinline__ short f2bf(float f) {
  unsigned u = __builtin_bit_cast(unsigned, f);
  unsigned r = (u + 0x7fffu + ((u >> 16) & 1u)) >> 16;  // RNE
  return (short)r;
}
__device__ __forceinline__ float bf2f(short s) {
  unsigned u = ((unsigned)(unsigned short)s) << 16;
  return __builtin_bit_cast(float, u);
}
// cheap nonlinearities: v_exp path + v_rcp (no IEEE-div expansion)
__device__ __forceinline__ float sigm_f(float x) {
  return __builtin_amdgcn_rcpf(1.0f + __expf(-x));
}
__device__ __forceinline__ float tanh_f(float x) {
  return 1.0f - 2.0f * __builtin_amdgcn_rcpf(1.0f + __expf(2.0f * x));
}

// ---- pre-pass: x [512][1024][64] fp32 -> per-block packet order bf16 hi/lo ----
__global__ __launch_bounds__(256, 4) void xconv(const float* __restrict__ x,
                                                short* __restrict__ xf) {
  const int g  = blockIdx.x * 256 + threadIdx.x;
  const int lq = g & 3;
  const int t  = (g >> 2) & (T_LEN - 1);
  const int chain = g >> 12;
  const int c   = chain & 1;
  const int blk = chain >> 1;
  const float* src = x + ((size_t)chain * T_LEN + t) * H + 8 * lq;
  float4 v0 = *reinterpret_cast<const float4*>(src);
  float4 v1 = *reinterpret_cast<const float4*>(src + 4);
  float4 v2 = *reinterpret_cast<const float4*>(src + 32);
  float4 v3 = *reinterpret_cast<const float4*>(src + 36);
  float a[8]  = {v0.x, v0.y, v0.z, v0.w, v1.x, v1.y, v1.z, v1.w};
  float c8[8] = {v2.x, v2.y, v2.z, v2.w, v3.x, v3.y, v3.z, v3.w};
  bf16x8 k0h, k0l, k1h, k1l;
#pragma unroll
  for (int e = 0; e < 8; ++e) {
    short h0 = f2bf(a[e]);
    k0h[e] = h0;
    k0l[e] = f2bf(a[e] - bf2f(h0));
    short h1 = f2bf(c8[e]);
    k1h[e] = h1;
    k1l[e] = f2bf(c8[e] - bf2f(h1));
  }
  short* dst = xf + (size_t)blk * XBLK_SHORTS + (size_t)t * XT_SHORTS +
               (lq * NB + c) * 32;
  *reinterpret_cast<bf16x8*>(dst + 0)  = k0h;
  *reinterpret_cast<bf16x8*>(dst + 8)  = k1h;
  *reinterpret_cast<bf16x8*>(dst + 16) = k0l;
  *reinterpret_cast<bf16x8*>(dst + 24) = k1l;
}

// 3-pass over ONE k-tile: hi·hi, lo·hi, hi·lo
__device__ __forceinline__ f32x4 mfma3(bf16x8 wh, bf16x8 wl, bf16x8 kh,
                                       bf16x8 kl, f32x4 acc) {
  acc = MFMA16(wh, kh, acc);
  acc = MFMA16(wl, kh, acc);
  acc = MFMA16(wh, kl, acc);
  return acc;
}

__global__ __launch_bounds__(NTHR, 1) void lstm_fused(
    const short* __restrict__ xf,
    const float* __restrict__ w_ih0, const float* __restrict__ w_hh0,
    const float* __restrict__ b_ih0, const float* __restrict__ b_hh0,
    const float* __restrict__ w_ih1, const float* __restrict__ w_hh1,
    const float* __restrict__ b_ih1, const float* __restrict__ b_hh1,
    const float* __restrict__ fc_w, const float* __restrict__ fc_b,
    float* __restrict__ out) {
  const int tid   = threadIdx.x;
  const int wv    = tid >> 6;
  const int group = wv >> 2;   // 0 = layer0 waves, 1 = layer1 waves (+gate duty)
  const int sw    = wv & 3;
  const int l     = tid & 63;
  const int b     = l & 15;
  const int lq    = l >> 4;
  const int blk   = blockIdx.x;
  const int chain0 = blk * NB;

  // h buffers: [buf][part hi/lo][kts][544 shorts]; slot map verified r4-r6.
  __shared__ __align__(16) short h0buf[2][2][2][544];
  __shared__ __align__(16) short h1buf[2][2][2][544];
  __shared__ __align__(16) float bias_s[2][256];
  __shared__ __align__(16) float zbuf[2][2][4][64];  // [L][chain][gate][h]
  __shared__ float fcw_s[H];
  __shared__ float hfin[NB][H];
  __shared__ volatile char lds_pad[56 * 1024];  // force 1 block/CU

  for (int i = tid; i < 2 * 2 * 2 * 544; i += NTHR) {
    ((short*)h0buf)[i] = 0;
    ((short*)h1buf)[i] = 0;
  }
  if (tid < 64) lds_pad[tid] = 0;
  if (tid < 256)      bias_s[0][tid] = b_ih0[tid] + b_hh0[tid];
  else                bias_s[1][tid - 256] = b_ih1[tid - 256] + b_hh1[tid - 256];
  if (tid < H) fcw_s[tid] = fc_w[tid];

  // ---- this wave's layer weights -> register frags (hi/lo) ----
  const float* wih = group ? w_ih1 : w_ih0;
  const float* whh = group ? w_hh1 : w_hh0;
  bf16x8 whi[4][4], wlo[4][4];
#pragma unroll
  for (int g = 0; g < 4; ++g) {
#pragma unroll
    for (int kt = 0; kt < 4; ++kt) {
      const int row = 64 * g + 16 * sw + b;
      const int k0  = 32 * kt + 8 * lq;
      const float* src = (k0 < 64) ? &wih[row * 64 + k0] : &whh[row * 64 + (k0 - 64)];
      float4 v0 = *reinterpret_cast<const float4*>(src);
      float4 v1 = *reinterpret_cast<const float4*>(src + 4);
      float vv[8] = {v0.x, v0.y, v0.z, v0.w, v1.x, v1.y, v1.z, v1.w};
      bf16x8 hi8, lo8;
#pragma unroll
      for (int e = 0; e < 8; ++e) {
        short hh = f2bf(vv[e]);
        hi8[e] = hh;
        lo8[e] = f2bf(vv[e] - bf2f(hh));
      }
      whi[g][kt] = hi8;
      wlo[g][kt] = lo8;
    }
  }

  __syncthreads();  // bias_s / h-buf zeros visible

  // ---- G0 prologue: accx = bias + W_ih0·x[0]; xc = x[1] ----
  const short* xfl = xf + (size_t)blk * XBLK_SHORTS + (size_t)(lq * NB + (l & 1)) * 32;
  f32x4 accx[4];
  bf16x8 xc0h, xc1h, xc0l, xc1l, xn0h, xn1h, xn0l, xn1l;
  if (group == 0) {
    bf16x8 a0h = *reinterpret_cast<const bf16x8*>(xfl + 0);
    bf16x8 a1h = *reinterpret_cast<const bf16x8*>(xfl + 8);
    bf16x8 a0l = *reinterpret_cast<const bf16x8*>(xfl + 16);
    bf16x8 a1l = *reinterpret_cast<const bf16x8*>(xfl + 24);
#pragma unroll
    for (int g = 0; g < 4; ++g) {
      f32x4 acc = *reinterpret_cast<const f32x4*>(&bias_s[0][64 * g + 16 * sw + 4 * lq]);
      acc = mfma3(whi[g][0], wlo[g][0], a0h, a0l, acc);
      acc = mfma3(whi[g][1], wlo[g][1], a1h, a1l, acc);
      accx[g] = acc;
    }
    const short* p = xfl + XT_SHORTS;
    xc0h = *reinterpret_cast<const bf16x8*>(p + 0);
    xc1h = *reinterpret_cast<const bf16x8*>(p + 8);
    xc0l = *reinterpret_cast<const bf16x8*>(p + 16);
    xc1l = *reinterpret_cast<const bf16x8*>(p + 24);
  }

  // reader offset (verified): slot (l>>4)*136 + (l&1)*8 shorts
  const int rslot = (l >> 4) * 136 + (l & 1) * 8;
  // gate task (group-1 threads): one (L, chain, h) per lane
  const int task = tid - 256;
  const int gL = task >> 7, gc = (task >> 6) & 1, gh = task & 63;
  // h-frag write slot (same map as verified r6 writer, f = gh, c = gc):
  const int gslot = (gh >> 5) * 544 + ((gh >> 3) & 3) * 136 + gc * 8 + (gh & 7);
  float gcstate = 0.0f;
  const f32x4 zf4 = {0.f, 0.f, 0.f, 0.f};

  for (int t = 0; t <= T_LEN; ++t) {
    const int cur = t & 1, nxt = cur ^ 1;

    // h0[t-1] frags: L0 recurrent side, L1 input side
    const short* p0 = &h0buf[cur][0][0][0] + rslot;
    bf16x8 r0h = *reinterpret_cast<const bf16x8*>(p0);
    bf16x8 r1h = *reinterpret_cast<const bf16x8*>(p0 + 544);
    bf16x8 r0l = *reinterpret_cast<const bf16x8*>(p0 + 1088);
    bf16x8 r1l = *reinterpret_cast<const bf16x8*>(p0 + 1632);

    if (group == 0) {
      if (t + 2 < T_LEN) {  // issue x[t+2] load early (consumed next iter)
        const short* p = xfl + (size_t)(t + 2) * XT_SHORTS;
        xn0h = *reinterpret_cast<const bf16x8*>(p + 0);
        xn1h = *reinterpret_cast<const bf16x8*>(p + 8);
        xn0l = *reinterpret_cast<const bf16x8*>(p + 16);
        xn1l = *reinterpret_cast<const bf16x8*>(p + 24);
      }
      if (t < T_LEN) {
        f32x4 aR0[4], aR1[4];
#pragma unroll
        for (int g = 0; g < 4; ++g) {
          aR0[g] = mfma3(whi[g][2], wlo[g][2], r0h, r0l, zf4);
          aR1[g] = mfma3(whi[g][3], wlo[g][3], r1h, r1l, zf4);
        }
        if (b < NB) {
#pragma unroll
          for (int g = 0; g < 4; ++g) {
            f32x4 z = (accx[g] + aR0[g]) + aR1[g];
            *reinterpret_cast<f32x4*>(&zbuf[0][b][g][16 * sw + 4 * lq]) = z;
          }
        } else {
          // keep the adds issued uniformly (negligible; avoids divergence)
#pragma unroll
          for (int g = 0; g < 4; ++g) aR0[g] = (accx[g] + aR0[g]) + aR1[g];
        }
      }
    } else {
      // L1: input side on h0[t-1], recurrent side on h1[t-2]
      const short* p1 = &h1buf[cur][0][0][0] + rslot;
      bf16x8 s0h = *reinterpret_cast<const bf16x8*>(p1);
      bf16x8 s1h = *reinterpret_cast<const bf16x8*>(p1 + 544);
      bf16x8 s0l = *reinterpret_cast<const bf16x8*>(p1 + 1088);
      bf16x8 s1l = *reinterpret_cast<const bf16x8*>(p1 + 1632);
      f32x4 aI0[4], aI1[4], aR0[4], aR1[4];
#pragma unroll
      for (int g = 0; g < 4; ++g) {
        f32x4 bi = *reinterpret_cast<const f32x4*>(&bias_s[1][64 * g + 16 * sw + 4 * lq]);
        aI0[g] = mfma3(whi[g][0], wlo[g][0], r0h, r0l, bi);
        aI1[g] = mfma3(whi[g][1], wlo[g][1], r1h, r1l, zf4);
        aR0[g] = mfma3(whi[g][2], wlo[g][2], s0h, s0l, zf4);
        aR1[g] = mfma3(whi[g][3], wlo[g][3], s1h, s1l, zf4);
      }
      if (b < NB) {
#pragma unroll
        for (int g = 0; g < 4; ++g) {
          f32x4 z = (aI0[g] + aI1[g]) + (aR0[g] + aR1[g]);
          *reinterpret_cast<f32x4*>(&zbuf[1][b][g][16 * sw + 4 * lq]) = z;
        }
      }
    }

    __syncthreads();  // z ready

    if (group == 0) {
      // precompute next step's input side (overlaps gate phase on the SIMD)
      if (t + 1 < T_LEN) {
#pragma unroll
        for (int g = 0; g < 4; ++g) {
          f32x4 acc = *reinterpret_cast<const f32x4*>(&bias_s[0][64 * g + 16 * sw + 4 * lq]);
          acc = mfma3(whi[g][0], wlo[g][0], xc0h, xc0l, acc);
          acc = mfma3(whi[g][1], wlo[g][1], xc1h, xc1l, acc);
          accx[g] = acc;
        }
      }
    } else {
      // gate phase: one task per lane, torch order i,f,g,o
      const bool gact = (gL == 0) ? (t < T_LEN) : (t >= 1);
      if (gact) {
        float zi = zbuf[gL][gc][0][gh];
        float zf = zbuf[gL][gc][1][gh];
        float zg = zbuf[gL][gc][2][gh];
        float zo = zbuf[gL][gc][3][gh];
        float ig = sigm_f(zi), fg = sigm_f(zf);
        float gg = tanh_f(zg), og = sigm_f(zo);
        gcstate = fg * gcstate + ig * gg;
        float hv = og * tanh_f(gcstate);
        if (gL == 1 && t == T_LEN) {
          hfin[gc][gh] = hv;
        } else {
          short hh = f2bf(hv);
          short ll = f2bf(hv - bf2f(hh));
          short* base = gL ? &h1buf[nxt][0][0][0] : &h0buf[nxt][0][0][0];
          base[gslot]        = hh;
          base[1088 + gslot] = ll;
        }
      }
    }

    __syncthreads();  // h[nxt] ready

    if (group == 0) { xc0h = xn0h; xc1h = xn1h; xc0l = xn0l; xc1l = xn1l; }
  }

  // ---- FC epilogue: out = fc_w . h2[T-1] + fc_b ----
  if (tid < NB) {
    float acc = fc_b[0];
#pragma unroll
    for (int h = 0; h < H; ++h) acc += fcw_s[h] * hfin[tid][h];
    out[chain0 + tid] = acc;
  }
}

extern "C" void kernel_launch(void* const* d_in, const int* in_sizes, int n_in,
                              void* d_out, int out_size, void* d_ws, size_t ws_size,
                              hipStream_t stream) {
  const float* x     = (const float*)d_in[0];
  const float* w_ih0 = (const float*)d_in[1];
  const float* w_hh0 = (const float*)d_in[2];
  const float* b_ih0 = (const float*)d_in[3];
  const float* b_hh0 = (const float*)d_in[4];
  const float* w_ih1 = (const float*)d_in[5];
  const float* w_hh1 = (const float*)d_in[6];
  const float* b_ih1 = (const float*)d_in[7];
  const float* b_hh1 = (const float*)d_in[8];
  const float* fc_w  = (const float*)d_in[9];
  const float* fc_b  = (const float*)d_in[10];
  float* out = (float*)d_out;

  short* xfrag = (short*)d_ws;  // 128 MiB workspace

  xconv<<<dim3(8192), dim3(256), 0, stream>>>(x, xfrag);
  lstm_fused<<<dim3(NBLK), dim3(NTHR), 0, stream>>>(
      xfrag, w_ih0, w_hh0, b_ih0, b_hh0, w_ih1, w_hh1, b_ih1, b_hh1,
      fc_w, fc_b, out);
}